// Round 19
// baseline (2409.883 us; speedup 1.0000x reference)
//
#include <hip/hip_runtime.h>

// GRU B=64, T=512, IN=128, H=512, L=2, OUT=1 (fp32 in/out).
// R16 (resubmit; Round 18 was a GPUAcquisitionTimeout, kernel never ran):
// R15 + early direct gate stores (drop hout + barrier 3).
//   Audit: no-barrier-3 ALONE was never tested -- R7 bundled it with fixN
//   (the storm cause; R8 proved fixN storms even WITH the barrier).
//   With h_prev register-carried (numerics proven R8/R11), dropping
//   barrier 3 is race-free: gates read only P (guarded by barrier 2) and
//   registers; t+1's P writes are after t+1's barrier 1, which gate waves
//   must also reach, so P reads complete first. The Alds h_prev read is
//   gone (register), so t+1 staging writes can't race gates.
//   Effect: stores issue 200-400cyc earlier (immediately per gate thread,
//   latency-pipelined, no barrier) -> consumers see valid tags sooner;
//   hout LDS round-trip and barrier 3 removed. Store transactions 64x16B
//   -> 256x4B: R15 showed transaction count is nearly free.
//   Retry path untouched: serialized fix4 + 16B sc1 probe (storm-safe).
// History: R9=1723 R10(remap)=2906 R11(reg-direct)=1935 R12(agent-spec)=1702
//          R13b=2561 R14=2601 R15(16B-ops)=1694 (best).

constexpr int Bb = 64, Tt = 512, DIN = 128, Hh = 512;
constexpr int BH = Bb * Hh;
constexpr int S0 = 644;    // LDS A-row stride (u32), layer0: 128 x + 512 h + 4 pad
constexpr int S1 = 1028;   // layer1: 512 h0 + 512 h1 + 4 pad
constexpr int PR = 20;     // partials row stride: conflict-free (2-way) writes

typedef float  f32x4  __attribute__((ext_vector_type(4)));
typedef short  bf16x8 __attribute__((ext_vector_type(8)));
typedef int    i32x4  __attribute__((ext_vector_type(4)));
typedef unsigned long long u64;

#define MFMA16 __builtin_amdgcn_mfma_f32_16x16x32_bf16

__device__ __forceinline__ unsigned rne_bf16(unsigned xb){
    return (xb + 0x7FFFu + ((xb >> 16) & 1u)) >> 16;
}
__device__ __forceinline__ unsigned pack_split(float x){
    unsigned hb = rne_bf16(__float_as_uint(x));
    float hf = __uint_as_float(hb << 16);
    unsigned lb = rne_bf16(__float_as_uint(x - hf));
    return (hb << 16) | lb;
}
__device__ __forceinline__ float unpack_f32(unsigned u){
    return __uint_as_float(u & 0xFFFF0000u) + __uint_as_float(u << 16);
}

union FragU { unsigned w[4]; bf16x8 v; };

__device__ __forceinline__ void make_wfrag(const float* p, bf16x8& wh, bf16x8& wl){
    FragU hi, lo;
#pragma unroll
    for (int i = 0; i < 4; ++i){
        unsigned pa = pack_split(p[2*i]), pb = pack_split(p[2*i+1]);
        hi.w[i] = (pa >> 16) | (pb & 0xFFFF0000u);
        lo.w[i] = (pa & 0xFFFFu) | (pb << 16);
    }
    wh = hi.v; wl = lo.v;
}
// hi word = [b3,b2,a3,a2], lo word = [b1,b0,a1,a0] -- one v_perm_b32 each.
__device__ __forceinline__ void make_afrag(const unsigned* u, bf16x8& ah, bf16x8& al){
    FragU hi, lo;
#pragma unroll
    for (int i = 0; i < 4; ++i){
        unsigned a = u[2*i], b = u[2*i+1];
        hi.w[i] = __builtin_amdgcn_perm(b, a, 0x07060302u);
        lo.w[i] = __builtin_amdgcn_perm(b, a, 0x05040100u);
    }
    ah = hi.v; al = lo.v;
}

__device__ __forceinline__ u64 ald64(const u64* p){
    return __hip_atomic_load(p, __ATOMIC_RELAXED, __HIP_MEMORY_SCOPE_AGENT);
}
__device__ __forceinline__ void ast32(unsigned* p, unsigned v){
    __hip_atomic_store(p, v, __ATOMIC_RELAXED, __HIP_MEMORY_SCOPE_AGENT);
}
// 16B speculative read via two relaxed agent loads (compiler batches the
// waitcnt across the whole initial probe batch).
__device__ __forceinline__ i32x4 ald128(const unsigned* p){
    u64 a = ald64((const u64*)p);
    u64 b = ald64((const u64*)p + 1);
    i32x4 v;
    v[0] = (int)(unsigned)a; v[1] = (int)(unsigned)(a >> 32);
    v[2] = (int)(unsigned)b; v[3] = (int)(unsigned)(b >> 32);
    return v;
}
// 16B device-scope load in ONE transaction (sc1; bypasses stale-capable
// cached copies). Internal vmcnt(0): only used in the serialized retry.
__device__ __forceinline__ i32x4 ald128a(const unsigned* p){
    i32x4 r;
    asm volatile("global_load_dwordx4 %0, %1, off sc1\n\t"
                 "s_waitcnt vmcnt(0)"
                 : "=v"(r) : "v"(p) : "memory");
    return r;
}

// all 4 words must have bit0 == tag
__device__ __forceinline__ bool bad4(const i32x4& v, unsigned tag){
    unsigned x = ((unsigned)v[0] ^ tag) | ((unsigned)v[1] ^ tag)
               | ((unsigned)v[2] ^ tag) | ((unsigned)v[3] ^ tag);
    return (x & 1u) != 0u;
}
// serial retry: SERIALIZED per chunk (rate limiter -- every parallel
// variant regressed: R7/R8/R13b/R14). 16B single-transaction probe.
__device__ __forceinline__ void fix4(const unsigned* p, unsigned tag, i32x4& v){
    if (bad4(v, tag)){
        for (;;){
            v = ald128a(p);
            if (!bad4(v, tag)) break;
            __builtin_amdgcn_s_sleep(1);
        }
    }
}

template<bool BIG>
__global__ __launch_bounds__(512, 1) void gru_main(
    const float* __restrict__ X,
    const float* __restrict__ Wih0, const float* __restrict__ Whh0,
    const float* __restrict__ bih0, const float* __restrict__ bhh0,
    const float* __restrict__ Wih1, const float* __restrict__ Whh1,
    const float* __restrict__ bih1, const float* __restrict__ bhh1,
    const float* __restrict__ fcW, const float* __restrict__ fcb,
    float* __restrict__ out,
    unsigned* hseq0, unsigned* hseq1)
{
    // Kill stale clean L1/L2 lines left from the previous graph replay.
    __builtin_amdgcn_fence(__ATOMIC_ACQUIRE, "agent");

    __shared__ unsigned Alds[16 * S1];
    __shared__ float P[8][3][16 * PR];

    const int tid  = threadIdx.x;
    const int lane = tid & 63;
    const int w    = tid >> 6;
    const bool isL1 = blockIdx.x >= 128;
    const int lb = isL1 ? (int)blockIdx.x - 128 : (int)blockIdx.x;
    const int m  = lb >> 5;                // batch tile 0..3
    const int cb = lb & 31;                // col-block 0..31
    const int c0 = cb * 16;
    const int STR  = isL1 ? S1 : S0;

    const bool active = isL1 || (w < 5);   // layer0 K=640 -> 5 waves x 128

    // ---- register-resident weight fragments (hi/lo split-bf16) ----
    bf16x8 whi[4][3], wlo[4][3];
    if (active){
        const int n = lane & 15;
#pragma unroll
        for (int ks = 0; ks < 4; ++ks){
            int kq = w * 128 + ks * 32 + (lane >> 4) * 8;
            const float* src; long kloc, rowlen;
            if (isL1){
                if (kq < 512){ src = Wih1; kloc = kq; } else { src = Whh1; kloc = kq - 512; }
                rowlen = 512;
            } else {
                if (kq < 128){ src = Wih0; kloc = kq; rowlen = 128; }
                else         { src = Whh0; kloc = kq - 128; rowlen = 512; }
            }
#pragma unroll
            for (int g = 0; g < 3; ++g){
                long row = (long)g * Hh + c0 + n;
                make_wfrag(src + row * rowlen + kloc, whi[ks][g], wlo[ks][g]);
            }
        }
    }
    // ---- biases for gate phase ----
    float Br = 0.f, Bz = 0.f, Bin = 0.f, Bhn = 0.f;
    if (tid < 256){
        int c = c0 + (tid & 15);
        const float* bi = isL1 ? bih1 : bih0;
        const float* bh = isL1 ? bhh1 : bhh0;
        Br  = bi[c] + bh[c];
        Bz  = bi[Hh + c] + bh[Hh + c];
        Bin = bi[2*Hh + c];
        Bhn = bh[2*Hh + c];
    }

    float hp = 0.f;                        // register-carried h_prev (gate threads)

    for (int t = 0; t < Tt; ++t){
        // ---- staging: agent-first speculative loads + serialized fix-up ----
        if (isL1){
            const unsigned* s0 = hseq0 + ((long)t * Bb + m*16) * (long)Hh;
            long r1 = BIG ? (long)(t-1) * BH : (long)((t-1) & 1) * BH;
            const unsigned* s1 = hseq1 + r1 + (long)(m*16) * Hh;
            unsigned tag1 = BIG ? 1u : (1u - (((unsigned)(t-1) >> 1) & 1u));
            const unsigned* a0[4]; const unsigned* a1[4];
            i32x4 v0[4], v1[4];
#pragma unroll
            for (int it = 0; it < 4; ++it){
                int j = it*512 + tid; int row = j >> 7, col = (j & 127) * 4;
                a0[it] = s0 + (long)row * Hh + col;
                v0[it] = ald128(a0[it]);
            }
            if (t > 0){
#pragma unroll
                for (int it = 0; it < 4; ++it){
                    int j = it*512 + tid; int row = j >> 7, col = (j & 127) * 4;
                    a1[it] = s1 + (long)row * Hh + col;
                    v1[it] = ald128(a1[it]);
                }
            }
#pragma unroll
            for (int it = 0; it < 4; ++it) fix4(a0[it], 1u, v0[it]);
            if (t > 0){
#pragma unroll
                for (int it = 0; it < 4; ++it) fix4(a1[it], tag1, v1[it]);
            } else {
#pragma unroll
                for (int it = 0; it < 4; ++it) v1[it] = i32x4{0,0,0,0};
            }
#pragma unroll
            for (int it = 0; it < 4; ++it){
                int j = it*512 + tid; int row = j >> 7, col = (j & 127) * 4;
                *(i32x4*)(Alds + row * S1 + col) = v0[it];
                *(i32x4*)(Alds + row * S1 + 512 + col) = v1[it];
            }
        } else {
            // X[t] fp32 (cached input) -> pack on the fly
            {
                int row = tid >> 5, c4 = (tid & 31) * 4;
                f32x4 xv = *(const f32x4*)(X + ((long)(m*16 + row) * Tt + t) * DIN + c4);
                i32x4 pv;
                pv[0] = (int)pack_split(xv[0]);
                pv[1] = (int)pack_split(xv[1]);
                pv[2] = (int)pack_split(xv[2]);
                pv[3] = (int)pack_split(xv[3]);
                *(i32x4*)(Alds + row * S0 + c4) = pv;
            }
            if (t > 0){
                const unsigned* s0 = hseq0 + ((long)(t-1) * Bb + m*16) * (long)Hh;
                const unsigned* a0[4]; i32x4 v0[4];
#pragma unroll
                for (int it = 0; it < 4; ++it){
                    int j = it*512 + tid; int row = j >> 7, col = (j & 127) * 4;
                    a0[it] = s0 + (long)row * Hh + col;
                    v0[it] = ald128(a0[it]);
                }
#pragma unroll
                for (int it = 0; it < 4; ++it) fix4(a0[it], 1u, v0[it]);
#pragma unroll
                for (int it = 0; it < 4; ++it){
                    int j = it*512 + tid; int row = j >> 7, col = (j & 127) * 4;
                    *(i32x4*)(Alds + row * S0 + 128 + col) = v0[it];
                }
            } else {
#pragma unroll
                for (int it = 0; it < 8; ++it){
                    int j = it*512 + tid;
                    *(u64*)(Alds + (j >> 8) * S0 + 128 + (j & 255) * 2) = 0ULL;
                }
            }
        }
        __syncthreads();

        // ---- MFMA: this wave's K-slice, tiles {r, z, nx-or-nh} ----
        if (active){
            f32x4 a0 = {0.f,0.f,0.f,0.f}, a1 = a0, a2 = a0;
            const unsigned* arow = Alds + (lane & 15) * STR + w * 128 + (lane >> 4) * 8;
#pragma unroll
            for (int ks = 0; ks < 4; ++ks){
                unsigned uu[8];
                *(i32x4*)&uu[0] = *(const i32x4*)(arow + ks*32);
                *(i32x4*)&uu[4] = *(const i32x4*)(arow + ks*32 + 4);
                bf16x8 ah, al; make_afrag(uu, ah, al);
                a0 = MFMA16(ah, whi[ks][0], a0, 0,0,0);
                a0 = MFMA16(ah, wlo[ks][0], a0, 0,0,0);
                a0 = MFMA16(al, whi[ks][0], a0, 0,0,0);
                a1 = MFMA16(ah, whi[ks][1], a1, 0,0,0);
                a1 = MFMA16(ah, wlo[ks][1], a1, 0,0,0);
                a1 = MFMA16(al, whi[ks][1], a1, 0,0,0);
                a2 = MFMA16(ah, whi[ks][2], a2, 0,0,0);
                a2 = MFMA16(ah, wlo[ks][2], a2, 0,0,0);
                a2 = MFMA16(al, whi[ks][2], a2, 0,0,0);
            }
            int q = lane >> 4, n = lane & 15;
#pragma unroll
            for (int r4 = 0; r4 < 4; ++r4){
                int idx = (q*4 + r4)*PR + n;
                P[w][0][idx] = a0[r4];
                P[w][1][idx] = a1[r4];
                P[w][2][idx] = a2[r4];
            }
        }
        __syncthreads();

        // ---- reduce partials + gates -> IMMEDIATE tagged u32 agent store ----
        // (h_prev register-carried; no hout, no barrier 3. Race-free: gates
        //  read only P [guarded by barrier 2] + registers; t+1's P writes
        //  are after t+1's barrier 1 which gate waves must also reach.)
        unsigned wtag = isL1 ? (BIG ? 1u : (1u - (((unsigned)t >> 1) & 1u))) : 1u;
        if (tid < 256){
            int bm = tid >> 4, n = tid & 15;
            int idx = bm * PR + n;
            float sr, sz, snx, snh;
            if (isL1){
                sr  = P[0][0][idx]+P[1][0][idx]+P[2][0][idx]+P[3][0][idx]
                    + P[4][0][idx]+P[5][0][idx]+P[6][0][idx]+P[7][0][idx];
                sz  = P[0][1][idx]+P[1][1][idx]+P[2][1][idx]+P[3][1][idx]
                    + P[4][1][idx]+P[5][1][idx]+P[6][1][idx]+P[7][1][idx];
                snx = P[0][2][idx]+P[1][2][idx]+P[2][2][idx]+P[3][2][idx];
                snh = P[4][2][idx]+P[5][2][idx]+P[6][2][idx]+P[7][2][idx];
            } else {
                sr  = P[0][0][idx]+P[1][0][idx]+P[2][0][idx]+P[3][0][idx]+P[4][0][idx];
                sz  = P[0][1][idx]+P[1][1][idx]+P[2][1][idx]+P[3][1][idx]+P[4][1][idx];
                snx = P[0][2][idx];
                snh = P[1][2][idx]+P[2][2][idx]+P[3][2][idx]+P[4][2][idx];
            }
            float r  = 1.f/(1.f + __expf(-(sr + Br)));
            float z  = 1.f/(1.f + __expf(-(sz + Bz)));
            float ee = __expf(2.f*(snx + Bin + r*(snh + Bhn)));
            float nn = 1.f - 2.f/(ee + 1.f);
            float hnew = (1.f - z)*nn + z*hp;
            hp = hnew;
            unsigned pv = (pack_split(hnew) & ~1u) | wtag;
            unsigned* base = isL1
                ? hseq1 + (BIG ? (long)t * BH : (long)(t & 1) * BH)
                : hseq0 + (long)t * BH;
            ast32(base + (long)(m*16 + bm) * Hh + c0 + n, pv);
        }
        // no barrier 3: waves flow straight into t+1 staging.
    }

    // ---- FC epilogue: one layer1 block per m, validated reads ----
    if (isL1 && cb == 31){
        unsigned ftag = BIG ? 1u : (1u - (((unsigned)(Tt-1) >> 1) & 1u));
        const unsigned* hb = hseq1 + (BIG ? (long)(Tt-1) * BH : (long)((Tt-1) & 1) * BH);
        int half = lane >> 5, l5 = lane & 31;
        int b = m*16 + w*2 + half;
        const u64* hrow = (const u64*)(hb + (long)b * Hh);
        float p = 0.f;
#pragma unroll
        for (int i = 0; i < 8; ++i){
            int k = l5 + 32*i;
            u64 v = ald64(hrow + k);
            while (((((unsigned)v ^ ftag) | ((unsigned)(v >> 32) ^ ftag)) & 1u) != 0u){
                __builtin_amdgcn_s_sleep(1);
                v = ald64(hrow + k);
            }
            p += unpack_f32((unsigned)v) * fcW[2*k]
               + unpack_f32((unsigned)(v >> 32)) * fcW[2*k+1];
        }
#pragma unroll
        for (int off = 16; off > 0; off >>= 1) p += __shfl_xor(p, off);
        if (l5 == 0) out[b] = p + fcb[0];
    }
}

extern "C" void kernel_launch(void* const* d_in, const int* in_sizes, int n_in,
                              void* d_out, int out_size, void* d_ws, size_t ws_size,
                              hipStream_t stream) {
    const float* X    = (const float*)d_in[0];
    const float* Wih0 = (const float*)d_in[1];
    const float* Whh0 = (const float*)d_in[2];
    const float* bih0 = (const float*)d_in[3];
    const float* bhh0 = (const float*)d_in[4];
    const float* Wih1 = (const float*)d_in[5];
    const float* Whh1 = (const float*)d_in[6];
    const float* bih1 = (const float*)d_in[7];
    const float* bhh1 = (const float*)d_in[8];
    const float* fcW  = (const float*)d_in[9];
    const float* fcb  = (const float*)d_in[10];
    float* out = (float*)d_out;

    // ws: hseq0 64 MiB | hseq1 64 MiB (BIG) or 256 KiB ring. No flags, no memset:
    // harness poisons ws to 0xAA (bit0=0 = invalid) before every launch.
    unsigned* hseq0 = (unsigned*)d_ws;
    unsigned* hseq1 = hseq0 + (long)Tt * BH;
    size_t need_big = (size_t)2 * Tt * BH * 4;    // 128 MiB
    bool big = ws_size >= need_big;

    if (big)
        gru_main<true><<<256, 512, 0, stream>>>(X, Wih0, Whh0, bih0, bhh0,
                                                Wih1, Whh1, bih1, bhh1, fcW, fcb,
                                                out, hseq0, hseq1);
    else
        gru_main<false><<<256, 512, 0, stream>>>(X, Wih0, Whh0, bih0, bhh0,
                                                 Wih1, Whh1, bih1, bhh1, fcW, fcb,
                                                 out, hseq0, hseq1);
}

// Round 20
// 1698.618 us; speedup vs baseline: 1.4187x; 1.4187x over previous
//
#include <hip/hip_runtime.h>

// GRU B=64, T=512, IN=128, H=512, L=2, OUT=1 (fp32 in/out).
// R17 = R15 restored (best verified: 1694us). R16 (drop barrier 3 + hout,
// immediate gate stores) regressed to 2410us: without barrier 3, gate-free
// waves 4-7 rush into t+1 staging and probe data whose producers haven't
// even COMPUTED yet -> guaranteed-stale probes lengthen retry chains
// (FETCH +48%, MfmaUtil 12->8.5). Barrier 3 is a load-bearing pacing
// mechanism: probes must launch only after stores issue.
// Final structure: lockstep 3-barrier step, hout staging, 16B sc1 single-
// transaction retry probes + 16B sc1 gate stores, agent-first speculative
// loads, SERIALIZED per-chunk retry (every parallel variant regressed).
// History: R9=1723 R10(remap)=2906 R11(reg-direct)=1935 R12(agent-spec)=1702
//          R13b=2561 R14=2601 R15=1694(best) R16(no-bar3)=2410.

constexpr int Bb = 64, Tt = 512, DIN = 128, Hh = 512;
constexpr int BH = Bb * Hh;
constexpr int S0 = 644;    // LDS A-row stride (u32), layer0: 128 x + 512 h + 4 pad
constexpr int S1 = 1028;   // layer1: 512 h0 + 512 h1 + 4 pad
constexpr int PR = 20;     // partials row stride: conflict-free (2-way) writes

typedef float  f32x4  __attribute__((ext_vector_type(4)));
typedef short  bf16x8 __attribute__((ext_vector_type(8)));
typedef int    i32x4  __attribute__((ext_vector_type(4)));
typedef unsigned long long u64;

#define MFMA16 __builtin_amdgcn_mfma_f32_16x16x32_bf16

__device__ __forceinline__ unsigned rne_bf16(unsigned xb){
    return (xb + 0x7FFFu + ((xb >> 16) & 1u)) >> 16;
}
__device__ __forceinline__ unsigned pack_split(float x){
    unsigned hb = rne_bf16(__float_as_uint(x));
    float hf = __uint_as_float(hb << 16);
    unsigned lb = rne_bf16(__float_as_uint(x - hf));
    return (hb << 16) | lb;
}
__device__ __forceinline__ float unpack_f32(unsigned u){
    return __uint_as_float(u & 0xFFFF0000u) + __uint_as_float(u << 16);
}

union FragU { unsigned w[4]; bf16x8 v; };

__device__ __forceinline__ void make_wfrag(const float* p, bf16x8& wh, bf16x8& wl){
    FragU hi, lo;
#pragma unroll
    for (int i = 0; i < 4; ++i){
        unsigned pa = pack_split(p[2*i]), pb = pack_split(p[2*i+1]);
        hi.w[i] = (pa >> 16) | (pb & 0xFFFF0000u);
        lo.w[i] = (pa & 0xFFFFu) | (pb << 16);
    }
    wh = hi.v; wl = lo.v;
}
// hi word = [b3,b2,a3,a2], lo word = [b1,b0,a1,a0] -- one v_perm_b32 each.
__device__ __forceinline__ void make_afrag(const unsigned* u, bf16x8& ah, bf16x8& al){
    FragU hi, lo;
#pragma unroll
    for (int i = 0; i < 4; ++i){
        unsigned a = u[2*i], b = u[2*i+1];
        hi.w[i] = __builtin_amdgcn_perm(b, a, 0x07060302u);
        lo.w[i] = __builtin_amdgcn_perm(b, a, 0x05040100u);
    }
    ah = hi.v; al = lo.v;
}

__device__ __forceinline__ u64 ald64(const u64* p){
    return __hip_atomic_load(p, __ATOMIC_RELAXED, __HIP_MEMORY_SCOPE_AGENT);
}
// 16B speculative read via two relaxed agent loads (compiler batches the
// waitcnt across the whole initial probe batch -- keep for issue phase).
__device__ __forceinline__ i32x4 ald128(const unsigned* p){
    u64 a = ald64((const u64*)p);
    u64 b = ald64((const u64*)p + 1);
    i32x4 v;
    v[0] = (int)(unsigned)a; v[1] = (int)(unsigned)(a >> 32);
    v[2] = (int)(unsigned)b; v[3] = (int)(unsigned)(b >> 32);
    return v;
}
// 16B device-scope load in ONE transaction (sc1 = device scope, bypasses
// stale-capable cached copies). Internal vmcnt(0): serialized retry only.
__device__ __forceinline__ i32x4 ald128a(const unsigned* p){
    i32x4 r;
    asm volatile("global_load_dwordx4 %0, %1, off sc1\n\t"
                 "s_waitcnt vmcnt(0)"
                 : "=v"(r) : "v"(p) : "memory");
    return r;
}
// 16B device-scope store in ONE transaction (tags in every word keep
// per-word visibility safe regardless of write atomicity).
__device__ __forceinline__ void ast128(unsigned* p, i32x4 v){
    asm volatile("global_store_dwordx4 %0, %1, off sc1"
                 :: "v"(p), "v"(v) : "memory");
}

// all 4 words must have bit0 == tag
__device__ __forceinline__ bool bad4(const i32x4& v, unsigned tag){
    unsigned x = ((unsigned)v[0] ^ tag) | ((unsigned)v[1] ^ tag)
               | ((unsigned)v[2] ^ tag) | ((unsigned)v[3] ^ tag);
    return (x & 1u) != 0u;
}
// serial retry: SERIALIZED per chunk (rate limiter -- R7/R8/R13b/R14
// lesson: every parallel-retry variant regresses). 16B single-transaction
// probe halves the retry's MALL transaction load vs 2x ald64.
__device__ __forceinline__ void fix4(const unsigned* p, unsigned tag, i32x4& v){
    if (bad4(v, tag)){
        for (;;){
            v = ald128a(p);
            if (!bad4(v, tag)) break;
            __builtin_amdgcn_s_sleep(1);
        }
    }
}

template<bool BIG>
__global__ __launch_bounds__(512, 1) void gru_main(
    const float* __restrict__ X,
    const float* __restrict__ Wih0, const float* __restrict__ Whh0,
    const float* __restrict__ bih0, const float* __restrict__ bhh0,
    const float* __restrict__ Wih1, const float* __restrict__ Whh1,
    const float* __restrict__ bih1, const float* __restrict__ bhh1,
    const float* __restrict__ fcW, const float* __restrict__ fcb,
    float* __restrict__ out,
    unsigned* hseq0, unsigned* hseq1)
{
    // Kill stale clean L1/L2 lines left from the previous graph replay.
    __builtin_amdgcn_fence(__ATOMIC_ACQUIRE, "agent");

    __shared__ unsigned Alds[16 * S1];
    __shared__ float P[8][3][16 * PR];
    __shared__ unsigned hout[256];

    const int tid  = threadIdx.x;
    const int lane = tid & 63;
    const int w    = tid >> 6;
    const bool isL1 = blockIdx.x >= 128;
    const int lb = isL1 ? (int)blockIdx.x - 128 : (int)blockIdx.x;
    const int m  = lb >> 5;                // batch tile 0..3
    const int cb = lb & 31;                // col-block 0..31
    const int c0 = cb * 16;
    const int STR  = isL1 ? S1 : S0;
    const int HOFF = isL1 ? 512 : 128;

    const bool active = isL1 || (w < 5);   // layer0 K=640 -> 5 waves x 128

    // ---- register-resident weight fragments (hi/lo split-bf16) ----
    bf16x8 whi[4][3], wlo[4][3];
    if (active){
        const int n = lane & 15;
#pragma unroll
        for (int ks = 0; ks < 4; ++ks){
            int kq = w * 128 + ks * 32 + (lane >> 4) * 8;
            const float* src; long kloc, rowlen;
            if (isL1){
                if (kq < 512){ src = Wih1; kloc = kq; } else { src = Whh1; kloc = kq - 512; }
                rowlen = 512;
            } else {
                if (kq < 128){ src = Wih0; kloc = kq; rowlen = 128; }
                else         { src = Whh0; kloc = kq - 128; rowlen = 512; }
            }
#pragma unroll
            for (int g = 0; g < 3; ++g){
                long row = (long)g * Hh + c0 + n;
                make_wfrag(src + row * rowlen + kloc, whi[ks][g], wlo[ks][g]);
            }
        }
    }
    // ---- biases for epilogue ----
    float Br = 0.f, Bz = 0.f, Bin = 0.f, Bhn = 0.f;
    if (tid < 256){
        int c = c0 + (tid & 15);
        const float* bi = isL1 ? bih1 : bih0;
        const float* bh = isL1 ? bhh1 : bhh0;
        Br  = bi[c] + bh[c];
        Bz  = bi[Hh + c] + bh[Hh + c];
        Bin = bi[2*Hh + c];
        Bhn = bh[2*Hh + c];
    }

    for (int t = 0; t < Tt; ++t){
        // ---- staging: agent-first speculative loads + serialized fix-up ----
        if (isL1){
            const unsigned* s0 = hseq0 + ((long)t * Bb + m*16) * (long)Hh;
            long r1 = BIG ? (long)(t-1) * BH : (long)((t-1) & 1) * BH;
            const unsigned* s1 = hseq1 + r1 + (long)(m*16) * Hh;
            unsigned tag1 = BIG ? 1u : (1u - (((unsigned)(t-1) >> 1) & 1u));
            const unsigned* a0[4]; const unsigned* a1[4];
            i32x4 v0[4], v1[4];
#pragma unroll
            for (int it = 0; it < 4; ++it){
                int j = it*512 + tid; int row = j >> 7, col = (j & 127) * 4;
                a0[it] = s0 + (long)row * Hh + col;
                v0[it] = ald128(a0[it]);
            }
            if (t > 0){
#pragma unroll
                for (int it = 0; it < 4; ++it){
                    int j = it*512 + tid; int row = j >> 7, col = (j & 127) * 4;
                    a1[it] = s1 + (long)row * Hh + col;
                    v1[it] = ald128(a1[it]);
                }
            }
#pragma unroll
            for (int it = 0; it < 4; ++it) fix4(a0[it], 1u, v0[it]);
            if (t > 0){
#pragma unroll
                for (int it = 0; it < 4; ++it) fix4(a1[it], tag1, v1[it]);
            } else {
#pragma unroll
                for (int it = 0; it < 4; ++it) v1[it] = i32x4{0,0,0,0};
            }
#pragma unroll
            for (int it = 0; it < 4; ++it){
                int j = it*512 + tid; int row = j >> 7, col = (j & 127) * 4;
                *(i32x4*)(Alds + row * S1 + col) = v0[it];
                *(i32x4*)(Alds + row * S1 + 512 + col) = v1[it];
            }
        } else {
            // X[t] fp32 (cached input) -> pack on the fly
            {
                int row = tid >> 5, c4 = (tid & 31) * 4;
                f32x4 xv = *(const f32x4*)(X + ((long)(m*16 + row) * Tt + t) * DIN + c4);
                i32x4 pv;
                pv[0] = (int)pack_split(xv[0]);
                pv[1] = (int)pack_split(xv[1]);
                pv[2] = (int)pack_split(xv[2]);
                pv[3] = (int)pack_split(xv[3]);
                *(i32x4*)(Alds + row * S0 + c4) = pv;
            }
            if (t > 0){
                const unsigned* s0 = hseq0 + ((long)(t-1) * Bb + m*16) * (long)Hh;
                const unsigned* a0[4]; i32x4 v0[4];
#pragma unroll
                for (int it = 0; it < 4; ++it){
                    int j = it*512 + tid; int row = j >> 7, col = (j & 127) * 4;
                    a0[it] = s0 + (long)row * Hh + col;
                    v0[it] = ald128(a0[it]);
                }
#pragma unroll
                for (int it = 0; it < 4; ++it) fix4(a0[it], 1u, v0[it]);
#pragma unroll
                for (int it = 0; it < 4; ++it){
                    int j = it*512 + tid; int row = j >> 7, col = (j & 127) * 4;
                    *(i32x4*)(Alds + row * S0 + 128 + col) = v0[it];
                }
            } else {
#pragma unroll
                for (int it = 0; it < 8; ++it){
                    int j = it*512 + tid;
                    *(u64*)(Alds + (j >> 8) * S0 + 128 + (j & 255) * 2) = 0ULL;
                }
            }
        }
        __syncthreads();

        // ---- MFMA: this wave's K-slice, tiles {r, z, nx-or-nh} ----
        if (active){
            f32x4 a0 = {0.f,0.f,0.f,0.f}, a1 = a0, a2 = a0;
            const unsigned* arow = Alds + (lane & 15) * STR + w * 128 + (lane >> 4) * 8;
#pragma unroll
            for (int ks = 0; ks < 4; ++ks){
                unsigned uu[8];
                *(i32x4*)&uu[0] = *(const i32x4*)(arow + ks*32);
                *(i32x4*)&uu[4] = *(const i32x4*)(arow + ks*32 + 4);
                bf16x8 ah, al; make_afrag(uu, ah, al);
                a0 = MFMA16(ah, whi[ks][0], a0, 0,0,0);
                a0 = MFMA16(ah, wlo[ks][0], a0, 0,0,0);
                a0 = MFMA16(al, whi[ks][0], a0, 0,0,0);
                a1 = MFMA16(ah, whi[ks][1], a1, 0,0,0);
                a1 = MFMA16(ah, wlo[ks][1], a1, 0,0,0);
                a1 = MFMA16(al, whi[ks][1], a1, 0,0,0);
                a2 = MFMA16(ah, whi[ks][2], a2, 0,0,0);
                a2 = MFMA16(ah, wlo[ks][2], a2, 0,0,0);
                a2 = MFMA16(al, whi[ks][2], a2, 0,0,0);
            }
            int q = lane >> 4, n = lane & 15;
#pragma unroll
            for (int r4 = 0; r4 < 4; ++r4){
                int idx = (q*4 + r4)*PR + n;
                P[w][0][idx] = a0[r4];
                P[w][1][idx] = a1[r4];
                P[w][2][idx] = a2[r4];
            }
        }
        __syncthreads();

        // ---- reduce partials + gates -> tagged packed h into LDS ----
        unsigned wtag = isL1 ? (BIG ? 1u : (1u - (((unsigned)t >> 1) & 1u))) : 1u;
        if (tid < 256){
            int bm = tid >> 4, n = tid & 15;
            int idx = bm * PR + n;
            float sr, sz, snx, snh;
            if (isL1){
                sr  = P[0][0][idx]+P[1][0][idx]+P[2][0][idx]+P[3][0][idx]
                    + P[4][0][idx]+P[5][0][idx]+P[6][0][idx]+P[7][0][idx];
                sz  = P[0][1][idx]+P[1][1][idx]+P[2][1][idx]+P[3][1][idx]
                    + P[4][1][idx]+P[5][1][idx]+P[6][1][idx]+P[7][1][idx];
                snx = P[0][2][idx]+P[1][2][idx]+P[2][2][idx]+P[3][2][idx];
                snh = P[4][2][idx]+P[5][2][idx]+P[6][2][idx]+P[7][2][idx];
            } else {
                sr  = P[0][0][idx]+P[1][0][idx]+P[2][0][idx]+P[3][0][idx]+P[4][0][idx];
                sz  = P[0][1][idx]+P[1][1][idx]+P[2][1][idx]+P[3][1][idx]+P[4][1][idx];
                snx = P[0][2][idx];
                snh = P[1][2][idx]+P[2][2][idx]+P[3][2][idx]+P[4][2][idx];
            }
            float r  = 1.f/(1.f + __expf(-(sr + Br)));
            float z  = 1.f/(1.f + __expf(-(sz + Bz)));
            float ee = __expf(2.f*(snx + Bin + r*(snh + Bhn)));
            float nn = 1.f - 2.f/(ee + 1.f);
            float hp = unpack_f32(Alds[bm*STR + HOFF + c0 + n]);
            float hnew = (1.f - z)*nn + z*hp;
            hout[tid] = (pack_split(hnew) & ~1u) | wtag;   // hout[bm*16 + n]
        }
        __syncthreads();

        // ---- 16B device-scope stores; NO ack wait, NO flag ----
        if (tid < 64){
            int bm = tid >> 2, k = (tid & 3) * 4;
            i32x4 v;
            v[0] = (int)hout[bm*16 + k];
            v[1] = (int)hout[bm*16 + k + 1];
            v[2] = (int)hout[bm*16 + k + 2];
            v[3] = (int)hout[bm*16 + k + 3];
            unsigned* base = isL1
                ? hseq1 + (BIG ? (long)t * BH : (long)(t & 1) * BH)
                : hseq0 + (long)t * BH;
            ast128(base + (long)(m*16 + bm) * Hh + c0 + k, v);
        }
    }

    // ---- FC epilogue: one layer1 block per m, validated reads ----
    if (isL1 && cb == 31){
        unsigned ftag = BIG ? 1u : (1u - (((unsigned)(Tt-1) >> 1) & 1u));
        const unsigned* hb = hseq1 + (BIG ? (long)(Tt-1) * BH : (long)((Tt-1) & 1) * BH);
        int half = lane >> 5, l5 = lane & 31;
        int b = m*16 + w*2 + half;
        const u64* hrow = (const u64*)(hb + (long)b * Hh);
        float p = 0.f;
#pragma unroll
        for (int i = 0; i < 8; ++i){
            int k = l5 + 32*i;
            u64 v = ald64(hrow + k);
            while (((((unsigned)v ^ ftag) | ((unsigned)(v >> 32) ^ ftag)) & 1u) != 0u){
                __builtin_amdgcn_s_sleep(1);
                v = ald64(hrow + k);
            }
            p += unpack_f32((unsigned)v) * fcW[2*k]
               + unpack_f32((unsigned)(v >> 32)) * fcW[2*k+1];
        }
#pragma unroll
        for (int off = 16; off > 0; off >>= 1) p += __shfl_xor(p, off);
        if (l5 == 0) out[b] = p + fcb[0];
    }
}

extern "C" void kernel_launch(void* const* d_in, const int* in_sizes, int n_in,
                              void* d_out, int out_size, void* d_ws, size_t ws_size,
                              hipStream_t stream) {
    const float* X    = (const float*)d_in[0];
    const float* Wih0 = (const float*)d_in[1];
    const float* Whh0 = (const float*)d_in[2];
    const float* bih0 = (const float*)d_in[3];
    const float* bhh0 = (const float*)d_in[4];
    const float* Wih1 = (const float*)d_in[5];
    const float* Whh1 = (const float*)d_in[6];
    const float* bih1 = (const float*)d_in[7];
    const float* bhh1 = (const float*)d_in[8];
    const float* fcW  = (const float*)d_in[9];
    const float* fcb  = (const float*)d_in[10];
    float* out = (float*)d_out;

    // ws: hseq0 64 MiB | hseq1 64 MiB (BIG) or 256 KiB ring. No flags, no memset:
    // harness poisons ws to 0xAA (bit0=0 = invalid) before every launch.
    unsigned* hseq0 = (unsigned*)d_ws;
    unsigned* hseq1 = hseq0 + (long)Tt * BH;
    size_t need_big = (size_t)2 * Tt * BH * 4;    // 128 MiB
    bool big = ws_size >= need_big;

    if (big)
        gru_main<true><<<256, 512, 0, stream>>>(X, Wih0, Whh0, bih0, bhh0,
                                                Wih1, Whh1, bih1, bhh1, fcW, fcb,
                                                out, hseq0, hseq1);
    else
        gru_main<false><<<256, 512, 0, stream>>>(X, Wih0, Whh0, bih0, bhh0,
                                                 Wih1, Whh1, bih1, bhh1, fcW, fcb,
                                                 out, hseq0, hseq1);
}